// Round 1
// baseline (2444.025 us; speedup 1.0000x reference)
//
#include <hip/hip_runtime.h>
#include <hip/hip_bf16.h>

// Performer (FAVOR+) attention, fp32.
// B=4 H=8 N=4096 D=64 M=256. Inputs: Q,K,V (bh,n,d) f32; mask (b,n) f32; proj (m,d) f32.
// Plan:
//  A: per-head partial max of xp_k           (grid 32x32, 128 rows/block)
//  B: reduce partials -> stab_k; zero ksum/ctx
//  C: phi_k accumulate -> ksum (256/head), ctx (256x64/head) via atomics
//  D: per-Q-row fused: xp_q (2 passes: max, then phi), D_inv, out = phi@ctx/D
// Trick: row-pointer loads (K/V rows in A/C, proj/ctx/ksum cols in D) are
// wave-uniform -> compiler emits s_load; per-thread operand lives in VGPRs ->
// inner loop is pure v_fmac_f32 v,s,v with no LDS.

constexpr int BB = 4, HH = 8, NN = 4096, DD = 64, MM = 256, BHN = BB * HH;
constexpr float SCALE = 0.3535533905932738f;  // 64^-0.25
constexpr float RATIO = 0.0625f;              // 256^-0.5
constexpr float EPSI  = 1e-4f;

// ---------------- Kernel A: partial max of xp_k ----------------
__global__ __launch_bounds__(256) void kmax_kernel(
    const float* __restrict__ K, const float* __restrict__ mask,
    const float* __restrict__ proj, float* __restrict__ partial) {
  const int bh = blockIdx.y;
  const int b  = bh / HH;
  const int m  = threadIdx.x;  // 0..255: this thread owns projection row m

  float pr[DD];
  const float* pm = proj + m * DD;
#pragma unroll
  for (int d = 0; d < DD; d += 4) {
    float4 t = *(const float4*)(pm + d);
    pr[d] = t.x; pr[d + 1] = t.y; pr[d + 2] = t.z; pr[d + 3] = t.w;
  }

  const float* Kb = K + (size_t)bh * NN * DD;
  const float* mb = mask + (size_t)b * NN;
  const int r0 = blockIdx.x * 128;

  float mx = -3.4e38f;
  for (int r = r0; r < r0 + 128; ++r) {
    const float* kr = Kb + (size_t)r * DD;  // wave-uniform -> s_load
    float a0 = 0.f, a1 = 0.f, a2 = 0.f, a3 = 0.f;
#pragma unroll
    for (int d = 0; d < DD; d += 4) {
      a0 = fmaf(kr[d + 0], pr[d + 0], a0);
      a1 = fmaf(kr[d + 1], pr[d + 1], a1);
      a2 = fmaf(kr[d + 2], pr[d + 2], a2);
      a3 = fmaf(kr[d + 3], pr[d + 3], a3);
    }
    float xp = ((a0 + a1) + (a2 + a3)) * (SCALE * mb[r]);
    mx = fmaxf(mx, xp);
  }

  // block-reduce max (4 waves)
  __shared__ float red[4];
#pragma unroll
  for (int off = 32; off; off >>= 1) mx = fmaxf(mx, __shfl_xor(mx, off));
  if ((threadIdx.x & 63) == 0) red[threadIdx.x >> 6] = mx;
  __syncthreads();
  if (threadIdx.x == 0) {
    float v = fmaxf(fmaxf(red[0], red[1]), fmaxf(red[2], red[3]));
    partial[bh * 32 + blockIdx.x] = v;
  }
}

// ---------------- Kernel B: finalize stab_k, zero accumulators ----------------
__global__ __launch_bounds__(256) void finalize_kernel(
    const float* __restrict__ partial, float* __restrict__ stabk,
    float* __restrict__ ksum, float* __restrict__ ctx) {
  const int bh = blockIdx.x;
  const int t  = threadIdx.x;
  if (t == 0) {
    float mx = partial[bh * 32];
    for (int i = 1; i < 32; ++i) mx = fmaxf(mx, partial[bh * 32 + i]);
    stabk[bh] = mx;
  }
  ksum[bh * MM + t] = 0.f;
  float* cb = ctx + (size_t)bh * MM * DD;
  for (int i = t; i < MM * DD; i += 256) cb[i] = 0.f;
}

// ---------------- Kernel C: phi_k -> ksum, ctx ----------------
__global__ __launch_bounds__(256) void phik_kernel(
    const float* __restrict__ K, const float* __restrict__ V,
    const float* __restrict__ mask, const float* __restrict__ proj,
    const float* __restrict__ stabk, float* __restrict__ ksum,
    float* __restrict__ ctx) {
  const int bh = blockIdx.y;
  const int b  = bh / HH;
  const int m  = threadIdx.x;

  float pr[DD];
  const float* pm = proj + m * DD;
#pragma unroll
  for (int d = 0; d < DD; d += 4) {
    float4 t = *(const float4*)(pm + d);
    pr[d] = t.x; pr[d + 1] = t.y; pr[d + 2] = t.z; pr[d + 3] = t.w;
  }

  float cacc[DD];
#pragma unroll
  for (int e = 0; e < DD; ++e) cacc[e] = 0.f;
  float ks = 0.f;

  const float stab = stabk[bh];
  const float* Kb = K + (size_t)bh * NN * DD;
  const float* Vb = V + (size_t)bh * NN * DD;
  const float* mb = mask + (size_t)b * NN;
  const int r0 = blockIdx.x * 256;

  for (int r = r0; r < r0 + 256; ++r) {
    const float* kr = Kb + (size_t)r * DD;  // uniform -> s_load
    float a0 = 0.f, a1 = 0.f, a2 = 0.f, a3 = 0.f;
    float s0 = 0.f, s1 = 0.f, s2 = 0.f, s3 = 0.f;
#pragma unroll
    for (int d = 0; d < DD; d += 4) {
      float k0 = kr[d + 0], k1 = kr[d + 1], k2 = kr[d + 2], k3 = kr[d + 3];
      a0 = fmaf(k0, pr[d + 0], a0);
      a1 = fmaf(k1, pr[d + 1], a1);
      a2 = fmaf(k2, pr[d + 2], a2);
      a3 = fmaf(k3, pr[d + 3], a3);
      s0 = fmaf(k0, k0, s0);
      s1 = fmaf(k1, k1, s1);
      s2 = fmaf(k2, k2, s2);
      s3 = fmaf(k3, k3, s3);
    }
    const float mk  = mb[r];
    const float msc = mk * SCALE;
    const float xp   = ((a0 + a1) + (a2 + a3)) * msc;
    const float diag = 0.5f * msc * msc * ((s0 + s1) + (s2 + s3));
    const float p = __expf(xp - diag - stab) + EPSI;
    ks += p;
    const float pmk = p * mk;  // v is masked
    const float* vr = Vb + (size_t)r * DD;  // uniform -> s_load
#pragma unroll
    for (int e = 0; e < DD; ++e) cacc[e] = fmaf(pmk, vr[e], cacc[e]);
  }

  atomicAdd(&ksum[bh * MM + m], ks * RATIO);

  // LDS transpose so the global atomic flush is lane-coalesced. 2 chunks of 32.
  __shared__ float lds[MM * 33];
  float* cg = ctx + (size_t)bh * MM * DD;
#pragma unroll
  for (int c = 0; c < 2; ++c) {
    __syncthreads();
#pragma unroll
    for (int j = 0; j < 32; ++j) lds[m * 33 + j] = cacc[c * 32 + j] * RATIO;
    __syncthreads();
    for (int i = threadIdx.x; i < MM * 32; i += 256) {
      int mm = i >> 5, e = i & 31;
      atomicAdd(&cg[mm * DD + c * 32 + e], lds[mm * 33 + e]);
    }
  }
}

// ---------------- Kernel D: fused Q side ----------------
__global__ __launch_bounds__(256, 2) void out_kernel(
    const float* __restrict__ Q, const float* __restrict__ proj,
    const float* __restrict__ ksum, const float* __restrict__ ctx,
    float* __restrict__ out) {
  const int bh = blockIdx.y;
  const int r  = blockIdx.x * 256 + threadIdx.x;  // one Q row per thread

  const float* qr = Q + ((size_t)bh * NN + r) * DD;
  float q[DD];
#pragma unroll
  for (int d = 0; d < DD; d += 4) {
    float4 t = *(const float4*)(qr + d);
    q[d] = t.x; q[d + 1] = t.y; q[d + 2] = t.z; q[d + 3] = t.w;
  }
  float s0 = 0.f, s1 = 0.f, s2 = 0.f, s3 = 0.f;
#pragma unroll
  for (int d = 0; d < DD; d += 4) {
    q[d + 0] *= SCALE; q[d + 1] *= SCALE; q[d + 2] *= SCALE; q[d + 3] *= SCALE;
    s0 = fmaf(q[d + 0], q[d + 0], s0);
    s1 = fmaf(q[d + 1], q[d + 1], s1);
    s2 = fmaf(q[d + 2], q[d + 2], s2);
    s3 = fmaf(q[d + 3], q[d + 3], s3);
  }
  const float diag = 0.5f * ((s0 + s1) + (s2 + s3));

  // pass 1: exact row max of xp_q (same FP ops as pass 2 -> exact match)
  float mx = -3.4e38f;
  for (int m = 0; m < MM; ++m) {
    const float* pm = proj + m * DD;  // uniform -> s_load
    float a0 = 0.f, a1 = 0.f, a2 = 0.f, a3 = 0.f;
#pragma unroll
    for (int d = 0; d < DD; d += 4) {
      a0 = fmaf(q[d + 0], pm[d + 0], a0);
      a1 = fmaf(q[d + 1], pm[d + 1], a1);
      a2 = fmaf(q[d + 2], pm[d + 2], a2);
      a3 = fmaf(q[d + 3], pm[d + 3], a3);
    }
    mx = fmaxf(mx, (a0 + a1) + (a2 + a3));
  }

  // pass 2: phi, D, out
  const float* ksb = ksum + bh * MM;
  const float* cgb = ctx + (size_t)bh * MM * DD;
  float o[DD];
#pragma unroll
  for (int e = 0; e < DD; ++e) o[e] = 0.f;
  float dsum = 0.f;

  for (int m = 0; m < MM; ++m) {
    const float* pm = proj + m * DD;  // uniform
    float a0 = 0.f, a1 = 0.f, a2 = 0.f, a3 = 0.f;
#pragma unroll
    for (int d = 0; d < DD; d += 4) {
      a0 = fmaf(q[d + 0], pm[d + 0], a0);
      a1 = fmaf(q[d + 1], pm[d + 1], a1);
      a2 = fmaf(q[d + 2], pm[d + 2], a2);
      a3 = fmaf(q[d + 3], pm[d + 3], a3);
    }
    const float xp = (a0 + a1) + (a2 + a3);
    const float p = __expf(xp - diag - mx) + EPSI;  // ratio cancels in out
    dsum = fmaf(p, ksb[m], dsum);
    const float* cm = cgb + m * DD;  // uniform
#pragma unroll
    for (int e = 0; e < DD; ++e) o[e] = fmaf(p, cm[e], o[e]);
  }

  const float dinv = 1.f / dsum;
  float* orow = out + ((size_t)bh * NN + r) * DD;
#pragma unroll
  for (int e = 0; e < DD; e += 4) {
    float4 t;
    t.x = o[e + 0] * dinv; t.y = o[e + 1] * dinv;
    t.z = o[e + 2] * dinv; t.w = o[e + 3] * dinv;
    *(float4*)(orow + e) = t;
  }
}

extern "C" void kernel_launch(void* const* d_in, const int* in_sizes, int n_in,
                              void* d_out, int out_size, void* d_ws, size_t ws_size,
                              hipStream_t stream) {
  const float* Q    = (const float*)d_in[0];
  const float* K    = (const float*)d_in[1];
  const float* V    = (const float*)d_in[2];
  const float* mask = (const float*)d_in[3];
  const float* proj = (const float*)d_in[4];
  float* out = (float*)d_out;

  float* wsf     = (float*)d_ws;
  float* partial = wsf;            // 32*32 = 1024
  float* stabk   = wsf + 1024;     // 32
  float* ksum    = wsf + 2048;     // 32*256 = 8192
  float* ctx     = wsf + 16384;    // 32*256*64 = 524288
  // total ~2.2 MB of ws

  kmax_kernel<<<dim3(32, BHN), 256, 0, stream>>>(K, mask, proj, partial);
  finalize_kernel<<<dim3(BHN), 256, 0, stream>>>(partial, stabk, ksum, ctx);
  phik_kernel<<<dim3(16, BHN), 256, 0, stream>>>(K, V, mask, proj, stabk, ksum, ctx);
  out_kernel<<<dim3(16, BHN), 256, 0, stream>>>(Q, proj, ksum, ctx, out);
}

// Round 2
// 808.568 us; speedup vs baseline: 3.0227x; 3.0227x over previous
//
#include <hip/hip_runtime.h>
#include <hip/hip_bf16.h>

// Performer (FAVOR+) attention, fp32. B=4 H=8 N=4096 D=64 M=256.
// Round-2: all bulk operands staged via coalesced global->LDS, consumed via
// same-address ds_read_b128 broadcasts (conflict-free). NO uniform-address
// global streaming (round-1's s_load chains were 70x slower than ideal).
// out_kernel is single-pass with online-max rescaling; eps terms split out
// via per-head ctxsum/kssum (max-independent).

constexpr int BB = 4, HH = 8, NN = 4096, DD = 64, MM = 256, BH = BB * HH;
constexpr float SCALE = 0.3535533905932738f;  // 64^-0.25
constexpr float RATIO = 0.0625f;              // 256^-0.5
constexpr float EPSI  = 1e-4f;
constexpr float NEGINF = -3.4e38f;

// ---------------- Kernel A: partial max of xp_k (2 proj rows / thread) ----
__global__ __launch_bounds__(128) void kmax_kernel(
    const float* __restrict__ K, const float* __restrict__ mask,
    const float* __restrict__ proj, float* __restrict__ partial) {
  const int bh = blockIdx.y, b = bh >> 3;
  const int t  = threadIdx.x;  // 0..127; owns proj rows t and t+128

  float4 pr0[16], pr1[16];
  {
    const float4* p0 = (const float4*)(proj + t * DD);
    const float4* p1 = (const float4*)(proj + (t + 128) * DD);
#pragma unroll
    for (int i = 0; i < 16; ++i) { pr0[i] = p0[i]; pr1[i] = p1[i]; }
  }

  __shared__ float ldsK[32 * DD];
  __shared__ float ldsM[32];
  __shared__ float red[2];

  const float* Kb = K + (size_t)bh * NN * DD;
  const float* mb = mask + (size_t)b * NN;
  const int r0 = blockIdx.x * 128;

  float mx = NEGINF;
  for (int ch = 0; ch < 4; ++ch) {
    const int rb = r0 + ch * 32;
    __syncthreads();
    // stage 32 K rows: 512 float4, coalesced
    const float4* src = (const float4*)(Kb + (size_t)rb * DD);
    float4* dst = (float4*)ldsK;
#pragma unroll
    for (int i = 0; i < 4; ++i) dst[t + i * 128] = src[t + i * 128];
    if (t < 32) ldsM[t] = mb[rb + t];
    __syncthreads();

    for (int r = 0; r < 32; ++r) {
      const float4* kr = (const float4*)(ldsK + r * DD);  // broadcast reads
      float a00 = 0, a01 = 0, a02 = 0, a03 = 0;
      float a10 = 0, a11 = 0, a12 = 0, a13 = 0;
#pragma unroll
      for (int i = 0; i < 16; ++i) {
        float4 kk = kr[i];
        a00 = fmaf(kk.x, pr0[i].x, a00); a01 = fmaf(kk.y, pr0[i].y, a01);
        a02 = fmaf(kk.z, pr0[i].z, a02); a03 = fmaf(kk.w, pr0[i].w, a03);
        a10 = fmaf(kk.x, pr1[i].x, a10); a11 = fmaf(kk.y, pr1[i].y, a11);
        a12 = fmaf(kk.z, pr1[i].z, a12); a13 = fmaf(kk.w, pr1[i].w, a13);
      }
      const float msc = SCALE * ldsM[r];
      const float x0 = ((a00 + a01) + (a02 + a03)) * msc;
      const float x1 = ((a10 + a11) + (a12 + a13)) * msc;
      mx = fmaxf(mx, fmaxf(x0, x1));
    }
  }

#pragma unroll
  for (int off = 32; off; off >>= 1) mx = fmaxf(mx, __shfl_xor(mx, off));
  if ((t & 63) == 0) red[t >> 6] = mx;
  __syncthreads();
  if (t == 0) partial[bh * 32 + blockIdx.x] = fmaxf(red[0], red[1]);
}

// ---------------- Kernel B: reduce partials -> stab_k --------------------
__global__ __launch_bounds__(64) void stab_kernel(
    const float* __restrict__ partial, float* __restrict__ stabk) {
  const int t = threadIdx.x;
  if (t < BH) {
    float mx = NEGINF;
    for (int i = 0; i < 32; ++i) mx = fmaxf(mx, partial[t * 32 + i]);
    stabk[t] = mx;
  }
}

// ---------------- Kernel C: phi_k -> ksum, ctx ---------------------------
__global__ __launch_bounds__(256) void phik_kernel(
    const float* __restrict__ K, const float* __restrict__ V,
    const float* __restrict__ mask, const float* __restrict__ proj,
    const float* __restrict__ stabk, float* __restrict__ ksum,
    float* __restrict__ ctx) {
  const int bh = blockIdx.y, b = bh >> 3;
  const int m  = threadIdx.x;

  __shared__ float smem[8448];            // 33 KB; main phase uses 16.6 KB
  float* ldsK = smem;                     // 2048
  float* ldsV = smem + 2048;              // 2048
  float* ldsM = smem + 4096;              // 32

  float4 pr[16];
  {
    const float4* pm = (const float4*)(proj + m * DD);
#pragma unroll
    for (int i = 0; i < 16; ++i) pr[i] = pm[i];
  }
  float4 ca[16];
#pragma unroll
  for (int i = 0; i < 16; ++i) ca[i] = make_float4(0.f, 0.f, 0.f, 0.f);
  float ks = 0.f;

  const float stab = stabk[bh];
  const float* Kb = K + (size_t)bh * NN * DD;
  const float* Vb = V + (size_t)bh * NN * DD;
  const float* mb = mask + (size_t)b * NN;
  const int r0 = blockIdx.x * 256;

  for (int ch = 0; ch < 8; ++ch) {
    const int rb = r0 + ch * 32;
    __syncthreads();
    const float4* sk = (const float4*)(Kb + (size_t)rb * DD);
    const float4* sv = (const float4*)(Vb + (size_t)rb * DD);
    float4* dk = (float4*)ldsK;
    float4* dv = (float4*)ldsV;
    dk[m] = sk[m]; dk[m + 256] = sk[m + 256];
    dv[m] = sv[m]; dv[m + 256] = sv[m + 256];
    if (m < 32) ldsM[m] = mb[rb + m];
    __syncthreads();

    for (int r = 0; r < 32; ++r) {
      const float4* kr = (const float4*)(ldsK + r * DD);  // broadcast
      float a0 = 0, a1 = 0, a2 = 0, a3 = 0;
      float s0 = 0, s1 = 0, s2 = 0, s3 = 0;
#pragma unroll
      for (int i = 0; i < 16; ++i) {
        float4 kk = kr[i];
        a0 = fmaf(kk.x, pr[i].x, a0); a1 = fmaf(kk.y, pr[i].y, a1);
        a2 = fmaf(kk.z, pr[i].z, a2); a3 = fmaf(kk.w, pr[i].w, a3);
        s0 = fmaf(kk.x, kk.x, s0);    s1 = fmaf(kk.y, kk.y, s1);
        s2 = fmaf(kk.z, kk.z, s2);    s3 = fmaf(kk.w, kk.w, s3);
      }
      const float mk  = ldsM[r];
      const float msc = mk * SCALE;
      const float xp   = ((a0 + a1) + (a2 + a3)) * msc;
      const float diag = 0.5f * msc * msc * ((s0 + s1) + (s2 + s3));
      const float p = __expf(xp - diag - stab) + EPSI;
      ks += p;
      const float pmk = p * mk;
      const float* vr = ldsV + r * DD;  // broadcast
      const float4* v4 = (const float4*)vr;
#pragma unroll
      for (int i = 0; i < 16; ++i) {
        float4 vv = v4[i];
        ca[i].x = fmaf(pmk, vv.x, ca[i].x);
        ca[i].y = fmaf(pmk, vv.y, ca[i].y);
        ca[i].z = fmaf(pmk, vv.z, ca[i].z);
        ca[i].w = fmaf(pmk, vv.w, ca[i].w);
      }
    }
  }

  atomicAdd(&ksum[bh * MM + m], ks * RATIO);

  // LDS transpose (reuse smem) so the global atomic flush is lane-coalesced.
  float* cg = ctx + (size_t)bh * MM * DD;
#pragma unroll
  for (int c = 0; c < 2; ++c) {
    __syncthreads();
#pragma unroll
    for (int i = 0; i < 8; ++i) {
      float4 v = ca[c * 8 + i];
      smem[m * 33 + i * 4 + 0] = v.x * RATIO;
      smem[m * 33 + i * 4 + 1] = v.y * RATIO;
      smem[m * 33 + i * 4 + 2] = v.z * RATIO;
      smem[m * 33 + i * 4 + 3] = v.w * RATIO;
    }
    __syncthreads();
    for (int i = threadIdx.x; i < MM * 32; i += 256) {
      int mm = i >> 5, e = i & 31;
      atomicAdd(&cg[mm * DD + c * 32 + e], smem[mm * 33 + e]);
    }
  }
}

// ---------------- Kernel C2: per-head ctxsum, kssum ----------------------
__global__ __launch_bounds__(256) void headsum_kernel(
    const float* __restrict__ ksum, const float* __restrict__ ctx,
    float* __restrict__ kssum, float* __restrict__ ctxsum) {
  const int bh = blockIdx.x, t = threadIdx.x;
  const int e = t & 63, q = t >> 6;
  __shared__ float red[256];

  const float* cb = ctx + (size_t)bh * MM * DD;
  float s = 0.f;
  for (int m = q * 64; m < q * 64 + 64; ++m) s += cb[m * DD + e];
  red[t] = s;
  __syncthreads();
  if (t < 64) ctxsum[bh * DD + t] = (red[t] + red[t + 64]) + (red[t + 128] + red[t + 192]);
  float kv = ksum[bh * MM + t];
  __syncthreads();
  red[t] = kv;
  __syncthreads();
  for (int off = 128; off >= 1; off >>= 1) {
    if (t < off) red[t] += red[t + off];
    __syncthreads();
  }
  if (t == 0) kssum[bh] = red[0];
}

// ---------------- Kernel D: fused Q side, online max ---------------------
__global__ __launch_bounds__(256) void out_kernel(
    const float* __restrict__ Q, const float* __restrict__ proj,
    const float* __restrict__ ksum, const float* __restrict__ ctx,
    const float* __restrict__ kssum, const float* __restrict__ ctxsum,
    float* __restrict__ out) {
  const int bh = blockIdx.y;
  const int t  = threadIdx.x;
  const int row = blockIdx.x * 256 + t;

  __shared__ float ldsP[64 * DD];  // 16 KB proj chunk
  __shared__ float ldsC[64 * DD];  // 16 KB ctx chunk
  __shared__ float ldsS[64];       // ksum chunk

  float4 q[16];
  {
    const float4* qr = (const float4*)(Q + ((size_t)bh * NN + row) * DD);
#pragma unroll
    for (int i = 0; i < 16; ++i) q[i] = qr[i];
  }
  float s0 = 0, s1 = 0, s2 = 0, s3 = 0;
#pragma unroll
  for (int i = 0; i < 16; ++i) {
    q[i].x *= SCALE; q[i].y *= SCALE; q[i].z *= SCALE; q[i].w *= SCALE;
    s0 = fmaf(q[i].x, q[i].x, s0); s1 = fmaf(q[i].y, q[i].y, s1);
    s2 = fmaf(q[i].z, q[i].z, s2); s3 = fmaf(q[i].w, q[i].w, s3);
  }
  const float diag = 0.5f * ((s0 + s1) + (s2 + s3));

  float4 o[16];
#pragma unroll
  for (int i = 0; i < 16; ++i) o[i] = make_float4(0.f, 0.f, 0.f, 0.f);
  float dsum = 0.f;
  float F = 0.f;         // current frame (stabilizer already applied)
  float M = NEGINF;      // true running max of xp

  const float* cb = ctx + (size_t)bh * MM * DD;
  const float* kb = ksum + bh * MM;

  for (int ch = 0; ch < 4; ++ch) {
    __syncthreads();
    const float4* ps = (const float4*)(proj + ch * 64 * DD);
    const float4* cs = (const float4*)(cb + ch * 64 * DD);
    float4* pd = (float4*)ldsP;
    float4* cd = (float4*)ldsC;
#pragma unroll
    for (int i = 0; i < 4; ++i) {
      pd[t + i * 256] = ps[t + i * 256];
      cd[t + i * 256] = cs[t + i * 256];
    }
    if (t < 64) ldsS[t] = kb[ch * 64 + t];
    __syncthreads();

    float cmax = NEGINF;
    for (int mm = 0; mm < 64; ++mm) {
      const float4* pm = (const float4*)(ldsP + mm * DD);  // broadcast
      float a0 = 0, a1 = 0, a2 = 0, a3 = 0;
#pragma unroll
      for (int i = 0; i < 16; ++i) {
        float4 pp = pm[i];
        a0 = fmaf(q[i].x, pp.x, a0); a1 = fmaf(q[i].y, pp.y, a1);
        a2 = fmaf(q[i].z, pp.z, a2); a3 = fmaf(q[i].w, pp.w, a3);
      }
      const float xp = (a0 + a1) + (a2 + a3);
      cmax = fmaxf(cmax, xp);
      const float p = __expf(xp - diag - F);
      dsum = fmaf(p, ldsS[mm], dsum);
      const float4* cm = (const float4*)(ldsC + mm * DD);  // broadcast
#pragma unroll
      for (int i = 0; i < 16; ++i) {
        float4 cc = cm[i];
        o[i].x = fmaf(p, cc.x, o[i].x);
        o[i].y = fmaf(p, cc.y, o[i].y);
        o[i].z = fmaf(p, cc.z, o[i].z);
        o[i].w = fmaf(p, cc.w, o[i].w);
      }
    }
    // frame boundary: rescale accumulators to the new running max
    M = fmaxf(M, cmax);
    const float fac = __expf(F - M);
    F = M;
    dsum *= fac;
#pragma unroll
    for (int i = 0; i < 16; ++i) {
      o[i].x *= fac; o[i].y *= fac; o[i].z *= fac; o[i].w *= fac;
    }
  }

  // epilogue: add max-independent eps terms, divide
  const float dinv = 1.f / (dsum + EPSI * kssum[bh]);
  const float4* csb = (const float4*)(ctxsum + bh * DD);
  float4* orow = (float4*)(out + ((size_t)bh * NN + row) * DD);
#pragma unroll
  for (int i = 0; i < 16; ++i) {
    float4 cs = csb[i];
    float4 r;
    r.x = (o[i].x + EPSI * cs.x) * dinv;
    r.y = (o[i].y + EPSI * cs.y) * dinv;
    r.z = (o[i].z + EPSI * cs.z) * dinv;
    r.w = (o[i].w + EPSI * cs.w) * dinv;
    orow[i] = r;
  }
}

extern "C" void kernel_launch(void* const* d_in, const int* in_sizes, int n_in,
                              void* d_out, int out_size, void* d_ws, size_t ws_size,
                              hipStream_t stream) {
  const float* Q    = (const float*)d_in[0];
  const float* K    = (const float*)d_in[1];
  const float* V    = (const float*)d_in[2];
  const float* mask = (const float*)d_in[3];
  const float* proj = (const float*)d_in[4];
  float* out = (float*)d_out;

  float* wsf     = (float*)d_ws;
  float* partial = wsf;          // 1024
  float* stabk   = wsf + 1024;   // 32
  float* kssum   = wsf + 1056;   // 32
  float* ctxsum  = wsf + 1088;   // 2048
  float* ksum    = wsf + 4096;   // 8192
  float* ctx     = wsf + 16384;  // 524288  -> end 540672 floats (~2.1 MB)

  // zero ksum..ctx (capture-safe async memset)
  hipMemsetAsync(wsf + 4096, 0, (540672 - 4096) * sizeof(float), stream);

  kmax_kernel<<<dim3(32, BH), 128, 0, stream>>>(K, mask, proj, partial);
  stab_kernel<<<1, 64, 0, stream>>>(partial, stabk);
  phik_kernel<<<dim3(16, BH), 256, 0, stream>>>(K, V, mask, proj, stabk, ksum, ctx);
  headsum_kernel<<<BH, 256, 0, stream>>>(ksum, ctx, kssum, ctxsum);
  out_kernel<<<dim3(16, BH), 256, 0, stream>>>(Q, proj, ksum, ctx, kssum, ctxsum, out);
}